// Round 1
// baseline (512.481 us; speedup 1.0000x reference)
//
#include <hip/hip_runtime.h>

// MultiTaskTrunkNetwork: 3x (Linear+Tanh) trunk [89->64->64->64] + per-task head [64->8]
// B=262144 rows, fp32 everywhere. Round 0: correctness-first fp32 VALU kernel.
//   - 64-thread blocks, 1 row/thread, input tile staged via LDS (coalesced)
//   - weights read wave-uniformly -> scalar loads (s_load) feeding v_fmac
//   - h[64] in registers, tanh = 1 - 2*rcp(exp(2x)+1)

constexpr int BN   = 262144;
constexpr int INF  = 89;
constexpr int HID  = 64;
constexpr int OUTF = 8;
constexpr int BROWS = 64;   // rows per block == threads per block (1 wave)

__device__ __forceinline__ float fast_tanh(float v) {
    // tanh(v) = 1 - 2/(exp(2v)+1); exact limits at +/-inf, branch-free
    float e = __expf(2.0f * v);
    return 1.0f - 2.0f * __builtin_amdgcn_rcpf(e + 1.0f);
}

__global__ __launch_bounds__(BROWS) void mtn_fused_kernel(
    const float* __restrict__ x,     // [B, 89]
    const int*   __restrict__ task,  // [B]
    const float* __restrict__ W0,    // [89, 64]
    const float* __restrict__ b0,    // [64]
    const float* __restrict__ W1,    // [64, 64]
    const float* __restrict__ b1,    // [64]
    const float* __restrict__ W2,    // [64, 64]
    const float* __restrict__ b2,    // [64]
    const float* __restrict__ hW,    // [50, 64, 8]
    const float* __restrict__ hB,    // [50, 8]
    float* __restrict__ out)         // [B, 8]
{
    __shared__ float xs[BROWS * INF];   // 22.8 KB

    const int t = threadIdx.x;
    const long long rowbase = (long long)blockIdx.x * BROWS;
    const long long gbase   = rowbase * INF;

    // ---- stage input tile, fully coalesced (89 rounds of 64 consecutive dwords)
    #pragma unroll 8
    for (int k = 0; k < INF; ++k) {
        xs[k * BROWS + t] = x[gbase + (long long)k * BROWS + t];
    }
    __syncthreads();

    const float* xr = &xs[t * INF];  // stride 89 dwords: 2-way bank alias (free)

    float ha[HID], hb[HID];

    // ---- layer 0: [89 -> 64]
    #pragma unroll
    for (int j = 0; j < HID; ++j) ha[j] = b0[j];
    for (int i = 0; i < INF; ++i) {
        const float xi = xr[i];
        const float* wr = &W0[i * HID];   // wave-uniform -> s_load
        #pragma unroll
        for (int j = 0; j < HID; ++j) ha[j] = fmaf(xi, wr[j], ha[j]);
    }
    #pragma unroll
    for (int j = 0; j < HID; ++j) ha[j] = fast_tanh(ha[j]);

    // ---- layer 1: [64 -> 64]
    #pragma unroll
    for (int j = 0; j < HID; ++j) hb[j] = b1[j];
    for (int i = 0; i < HID; ++i) {
        const float xi = ha[i];
        const float* wr = &W1[i * HID];
        #pragma unroll
        for (int j = 0; j < HID; ++j) hb[j] = fmaf(xi, wr[j], hb[j]);
    }
    #pragma unroll
    for (int j = 0; j < HID; ++j) hb[j] = fast_tanh(hb[j]);

    // ---- layer 2: [64 -> 64]
    #pragma unroll
    for (int j = 0; j < HID; ++j) ha[j] = b2[j];
    for (int i = 0; i < HID; ++i) {
        const float xi = hb[i];
        const float* wr = &W2[i * HID];
        #pragma unroll
        for (int j = 0; j < HID; ++j) ha[j] = fmaf(xi, wr[j], ha[j]);
    }
    #pragma unroll
    for (int j = 0; j < HID; ++j) ha[j] = fast_tanh(ha[j]);

    // ---- per-task head: [64 -> 8], fp32 gather (102 KB total -> L2 resident)
    const long long row = rowbase + t;
    const int tk = task[row];
    const float* Wg = hW + (long long)tk * (HID * OUTF);
    const float* bg = hB + tk * OUTF;

    float acc[OUTF];
    #pragma unroll
    for (int o = 0; o < OUTF; ++o) acc[o] = bg[o];

    for (int i = 0; i < HID; ++i) {
        const float hv = ha[i];
        const float4 wlo = *reinterpret_cast<const float4*>(Wg + i * OUTF);
        const float4 whi = *reinterpret_cast<const float4*>(Wg + i * OUTF + 4);
        acc[0] = fmaf(hv, wlo.x, acc[0]);
        acc[1] = fmaf(hv, wlo.y, acc[1]);
        acc[2] = fmaf(hv, wlo.z, acc[2]);
        acc[3] = fmaf(hv, wlo.w, acc[3]);
        acc[4] = fmaf(hv, whi.x, acc[4]);
        acc[5] = fmaf(hv, whi.y, acc[5]);
        acc[6] = fmaf(hv, whi.z, acc[6]);
        acc[7] = fmaf(hv, whi.w, acc[7]);
    }

    float4* orow = reinterpret_cast<float4*>(out + row * OUTF);
    orow[0] = make_float4(acc[0], acc[1], acc[2], acc[3]);
    orow[1] = make_float4(acc[4], acc[5], acc[6], acc[7]);
}

extern "C" void kernel_launch(void* const* d_in, const int* in_sizes, int n_in,
                              void* d_out, int out_size, void* d_ws, size_t ws_size,
                              hipStream_t stream) {
    const float* x    = (const float*)d_in[0];
    const int*   task = (const int*)  d_in[1];
    const float* W0   = (const float*)d_in[2];
    const float* b0   = (const float*)d_in[3];
    const float* W1   = (const float*)d_in[4];
    const float* b1   = (const float*)d_in[5];
    const float* W2   = (const float*)d_in[6];
    const float* b2   = (const float*)d_in[7];
    const float* hW   = (const float*)d_in[8];
    const float* hB   = (const float*)d_in[9];
    float* out = (float*)d_out;

    dim3 grid(BN / BROWS);   // 4096 blocks
    dim3 block(BROWS);
    mtn_fused_kernel<<<grid, block, 0, stream>>>(x, task, W0, b0, W1, b1, W2, b2,
                                                 hW, hB, out);
}

// Round 2
// 196.158 us; speedup vs baseline: 2.6126x; 2.6126x over previous
//
#include <hip/hip_runtime.h>

// MultiTaskTrunkNetwork: 3x (Linear+Tanh) trunk [89->64->64->64] + per-task head [64->8]
// Round 2: spill-free fp32 VALU kernel.
//   - 256-thread blocks (4 waves), 64 rows/block: lane = row, wave = j-band of 16
//   - per-thread state: acc[16] (no spills); h round-trips through padded LDS
//   - weights read via wave-uniform pointers (readfirstlane'd band) -> s_load + v_fmac
//   - one 22.8 KB LDS buffer aliased for x-tile and h (sync-guarded)

constexpr int BN    = 262144;
constexpr int INF   = 89;
constexpr int HID   = 64;
constexpr int OUTF  = 8;
constexpr int ROWS  = 64;          // rows per block
constexpr int NTHR  = 256;         // 4 waves
constexpr int JB    = 16;          // hidden outputs per wave (64 / 4)
constexpr int XS_ELEMS  = ROWS * INF;   // 5696 floats = 22784 B
constexpr int HS_STRIDE = HID + 1;      // 65: conflict-free stride-i reads

__device__ __forceinline__ float fast_tanh(float v) {
    // tanh(v) = 1 - 2/(exp(2v)+1); exact limits at +/-inf, branch-free
    float e = __expf(2.0f * v);
    return 1.0f - 2.0f * __builtin_amdgcn_rcpf(e + 1.0f);
}

__global__ __launch_bounds__(NTHR) void mtn_fused_kernel(
    const float* __restrict__ x,     // [B, 89]
    const int*   __restrict__ task,  // [B]
    const float* __restrict__ W0,    // [89, 64]
    const float* __restrict__ b0,    // [64]
    const float* __restrict__ W1,    // [64, 64]
    const float* __restrict__ b1,    // [64]
    const float* __restrict__ W2,    // [64, 64]
    const float* __restrict__ b2,    // [64]
    const float* __restrict__ hW,    // [50, 64, 8]
    const float* __restrict__ hB,    // [50, 8]
    float* __restrict__ out)         // [B, 8]
{
    __shared__ float smem[XS_ELEMS];   // x-tile; later aliased as h[64][65]

    const int t    = threadIdx.x;
    const int row  = t & 63;                                   // lane = row
    const int band = t >> 6;                                   // wave id 0..3
    const int jb   = __builtin_amdgcn_readfirstlane(band * JB); // wave-uniform j base
    const long long rowbase = (long long)blockIdx.x * ROWS;

    // ---- stage x tile [64 x 89], coalesced float4 (block offset 22784 B is 16B-aligned)
    {
        const float4* src = reinterpret_cast<const float4*>(x + rowbase * INF);
        float4*       dst = reinterpret_cast<float4*>(smem);
        for (int e = t; e < XS_ELEMS / 4; e += NTHR) dst[e] = src[e];
    }
    __syncthreads();

    float acc[JB];

    // ---- layer 0: [89 -> 64], this wave computes j = jb..jb+15 for all 64 rows
    #pragma unroll
    for (int j = 0; j < JB; ++j) acc[j] = b0[jb + j];
    {
        const float* xr = &smem[row * INF];       // banks (25*row+i)%32: conflict-free
        #pragma unroll 8
        for (int i = 0; i < INF; ++i) {
            const float xi = xr[i];
            const float* wr = &W0[i * HID + jb];  // wave-uniform -> s_load
            #pragma unroll
            for (int j = 0; j < JB; ++j) acc[j] = fmaf(xi, wr[j], acc[j]);
        }
    }
    #pragma unroll
    for (int j = 0; j < JB; ++j) acc[j] = fast_tanh(acc[j]);
    __syncthreads();                               // all x reads done before overwrite
    #pragma unroll
    for (int j = 0; j < JB; ++j) smem[row * HS_STRIDE + jb + j] = acc[j];
    __syncthreads();

    // ---- layer 1: [64 -> 64]
    #pragma unroll
    for (int j = 0; j < JB; ++j) acc[j] = b1[jb + j];
    {
        const float* xr = &smem[row * HS_STRIDE]; // banks (row+i)%32: conflict-free
        #pragma unroll 8
        for (int i = 0; i < HID; ++i) {
            const float xi = xr[i];
            const float* wr = &W1[i * HID + jb];
            #pragma unroll
            for (int j = 0; j < JB; ++j) acc[j] = fmaf(xi, wr[j], acc[j]);
        }
    }
    #pragma unroll
    for (int j = 0; j < JB; ++j) acc[j] = fast_tanh(acc[j]);
    __syncthreads();
    #pragma unroll
    for (int j = 0; j < JB; ++j) smem[row * HS_STRIDE + jb + j] = acc[j];
    __syncthreads();

    // ---- layer 2: [64 -> 64]
    #pragma unroll
    for (int j = 0; j < JB; ++j) acc[j] = b2[jb + j];
    {
        const float* xr = &smem[row * HS_STRIDE];
        #pragma unroll 8
        for (int i = 0; i < HID; ++i) {
            const float xi = xr[i];
            const float* wr = &W2[i * HID + jb];
            #pragma unroll
            for (int j = 0; j < JB; ++j) acc[j] = fmaf(xi, wr[j], acc[j]);
        }
    }
    #pragma unroll
    for (int j = 0; j < JB; ++j) acc[j] = fast_tanh(acc[j]);
    __syncthreads();
    #pragma unroll
    for (int j = 0; j < JB; ++j) smem[row * HS_STRIDE + jb + j] = acc[j];
    __syncthreads();

    // ---- per-task head: thread (row, band) computes outputs o = band*2, band*2+1
    const long long grow = rowbase + row;
    const int tk = task[grow];
    const float* Wg = hW + (size_t)tk * (HID * OUTF) + band * 2;  // 8B-aligned
    float a0 = hB[tk * OUTF + band * 2];
    float a1 = hB[tk * OUTF + band * 2 + 1];
    {
        const float* hr = &smem[row * HS_STRIDE];
        #pragma unroll 8
        for (int i = 0; i < HID; ++i) {
            const float hv = hr[i];
            const float2 w = *reinterpret_cast<const float2*>(Wg + i * OUTF);
            a0 = fmaf(hv, w.x, a0);
            a1 = fmaf(hv, w.y, a1);
        }
    }
    *reinterpret_cast<float2*>(out + grow * OUTF + band * 2) = make_float2(a0, a1);
}

extern "C" void kernel_launch(void* const* d_in, const int* in_sizes, int n_in,
                              void* d_out, int out_size, void* d_ws, size_t ws_size,
                              hipStream_t stream) {
    const float* x    = (const float*)d_in[0];
    const int*   task = (const int*)  d_in[1];
    const float* W0   = (const float*)d_in[2];
    const float* b0   = (const float*)d_in[3];
    const float* W1   = (const float*)d_in[4];
    const float* b1   = (const float*)d_in[5];
    const float* W2   = (const float*)d_in[6];
    const float* b2   = (const float*)d_in[7];
    const float* hW   = (const float*)d_in[8];
    const float* hB   = (const float*)d_in[9];
    float* out = (float*)d_out;

    dim3 grid(BN / ROWS);    // 4096 blocks
    dim3 block(NTHR);
    mtn_fused_kernel<<<grid, block, 0, stream>>>(x, task, W0, b0, W1, b1, W2, b2,
                                                 hW, hB, out);
}

// Round 3
// 71.824 us; speedup vs baseline: 7.1352x; 2.7311x over previous
//
#include <hip/hip_runtime.h>
#include <stdint.h>
#include <stddef.h>

// MultiTaskTrunkNetwork: 3x (Linear+Tanh) [89->64->64->64] + per-task head [64->8]
// Round 3: fp16 MFMA trunk, transposed orientation (feat=MFMA rows, batch=cols).
//   - wave-private pipeline: 32 batch rows/wave, no __syncthreads anywhere
//   - prep kernel converts weights to f16 (transposed, K-padded) into d_ws
//   - inter-layer h: 8x ds_write_b64 + 4x ds_read_b128 per wave (LDS [32][72] f16)
//   - head: fp32 math, f16 weight gather from L2

typedef _Float16 half8 __attribute__((ext_vector_type(8)));
typedef _Float16 half4 __attribute__((ext_vector_type(4)));
typedef float    f32x4 __attribute__((ext_vector_type(4)));

constexpr int BN = 262144, INF = 89, HID = 64, OUTF = 8, NTASK = 50;
constexpr int NTHR = 256;     // 4 waves
constexpr int ROWS = 128;     // batch rows per block (32 per wave)
constexpr int HP   = 72;      // LDS h pitch in f16 (144 B: 16B-aligned, good banks)

// d_ws layout (bytes)
constexpr int W0T_OFF = 0;        // [64][96] f16, zero-padded k>=89
constexpr int W1T_OFF = 12288;    // [64][64] f16
constexpr int W2T_OFF = 20480;    // [64][64] f16
constexpr int HW_OFF  = 28672;    // [50][64][8] f16

__device__ __forceinline__ float fast_tanh(float v) {
    float e = __expf(2.0f * v);
    return 1.0f - 2.0f * __builtin_amdgcn_rcpf(e + 1.0f);
}

__global__ void prep_kernel(const float* __restrict__ W0, const float* __restrict__ W1,
                            const float* __restrict__ W2, const float* __restrict__ hW,
                            _Float16* __restrict__ ws) {
    const int tid = blockIdx.x * blockDim.x + threadIdx.x;
    const int stride = gridDim.x * blockDim.x;
    _Float16* w0t = ws + W0T_OFF / 2;
    _Float16* w1t = ws + W1T_OFF / 2;
    _Float16* w2t = ws + W2T_OFF / 2;
    _Float16* hw  = ws + HW_OFF / 2;
    for (int i = tid; i < 64 * 96; i += stride) {       // W0T[n][k], pad k>=89 with 0
        int n = i / 96, k = i % 96;
        w0t[i] = (_Float16)(k < INF ? W0[k * HID + n] : 0.0f);
    }
    for (int i = tid; i < 64 * 64; i += stride) {       // W1T/W2T[n][k]
        int n = i / 64, k = i % 64;
        w1t[i] = (_Float16)W1[k * HID + n];
        w2t[i] = (_Float16)W2[k * HID + n];
    }
    for (int i = tid; i < NTASK * HID * OUTF; i += stride)
        hw[i] = (_Float16)hW[i];
}

__global__ __launch_bounds__(NTHR, 4) void mtn_mfma_kernel(
    const float* __restrict__ x,     // [B, 89]
    const int*   __restrict__ task,  // [B]
    const float* __restrict__ b0, const float* __restrict__ b1,
    const float* __restrict__ b2,
    const float* __restrict__ hB,    // [50, 8] fp32
    const _Float16* __restrict__ ws, // converted weights
    float* __restrict__ out)         // [B, 8]
{
    __shared__ _Float16 hs[4][32][HP];   // per-wave h tile [batch][feat]

    const int t = threadIdx.x;
    const int w = t >> 6;            // wave 0..3
    const int l = t & 63;
    const int c = l & 15;            // MFMA col (batch) / A row (feat)
    const int g = l >> 4;            // k-group / D row-group
    const int rowbase = blockIdx.x * ROWS + w * 32;

    const _Float16* w0t  = ws + W0T_OFF / 2;
    const _Float16* w1t  = ws + W1T_OFF / 2;
    const _Float16* w2t  = ws + W2T_OFF / 2;
    const _Float16* hw16 = ws + HW_OFF / 2;

    f32x4 acc[4][2];   // [feat-tile][batch-tile], reused per layer

    // ================= layer 0: K=96 (89 padded), B-frags from global x =================
    #pragma unroll
    for (int ft = 0; ft < 4; ++ft) {
        f32x4 bv = *(const f32x4*)(b0 + ft * 16 + g * 4);
        acc[ft][0] = bv; acc[ft][1] = bv;
    }
    #pragma unroll
    for (int kk = 0; kk < 3; ++kk) {
        half8 bf[2];
        #pragma unroll
        for (int bt = 0; bt < 2; ++bt) {
            const size_t batch = (size_t)(rowbase + bt * 16 + c);
            const int k0 = kk * 32 + g * 8;
            half8 hb;
            if (k0 == 88) {                       // kk==2 && g==3: only k=88 valid
                float v = x[batch * INF + 88];
                hb = half8{(_Float16)v, (_Float16)0, (_Float16)0, (_Float16)0,
                           (_Float16)0, (_Float16)0, (_Float16)0, (_Float16)0};
            } else {                              // k0..k0+7 all < 89
                float v[8];
                __builtin_memcpy(v, x + batch * INF + k0, 32);
                #pragma unroll
                for (int i2 = 0; i2 < 8; ++i2) hb[i2] = (_Float16)v[i2];
            }
            bf[bt] = hb;
        }
        #pragma unroll
        for (int ft = 0; ft < 4; ++ft) {
            half8 af = *(const half8*)(w0t + (ft * 16 + c) * 96 + kk * 32 + g * 8);
            acc[ft][0] = __builtin_amdgcn_mfma_f32_16x16x32_f16(af, bf[0], acc[ft][0], 0, 0, 0);
            acc[ft][1] = __builtin_amdgcn_mfma_f32_16x16x32_f16(af, bf[1], acc[ft][1], 0, 0, 0);
        }
    }
    #pragma unroll
    for (int ft = 0; ft < 4; ++ft)
        #pragma unroll
        for (int bt = 0; bt < 2; ++bt) {
            half4 hv;
            #pragma unroll
            for (int r = 0; r < 4; ++r) hv[r] = (_Float16)fast_tanh(acc[ft][bt][r]);
            *(half4*)&hs[w][bt * 16 + c][ft * 16 + g * 4] = hv;   // 8B store
        }

    // ================= layers 1,2: K=64, B-frags from wave-private LDS =================
    #pragma unroll
    for (int layer = 0; layer < 2; ++layer) {
        const _Float16* WT  = layer ? w2t : w1t;
        const float*    bia = layer ? b2  : b1;
        #pragma unroll
        for (int ft = 0; ft < 4; ++ft) {
            f32x4 bv = *(const f32x4*)(bia + ft * 16 + g * 4);
            acc[ft][0] = bv; acc[ft][1] = bv;
        }
        #pragma unroll
        for (int kk = 0; kk < 2; ++kk) {
            half8 bf[2];
            #pragma unroll
            for (int bt = 0; bt < 2; ++bt)
                bf[bt] = *(const half8*)&hs[w][bt * 16 + c][kk * 32 + g * 8];  // 16B read
            #pragma unroll
            for (int ft = 0; ft < 4; ++ft) {
                half8 af = *(const half8*)(WT + (ft * 16 + c) * 64 + kk * 32 + g * 8);
                acc[ft][0] = __builtin_amdgcn_mfma_f32_16x16x32_f16(af, bf[0], acc[ft][0], 0, 0, 0);
                acc[ft][1] = __builtin_amdgcn_mfma_f32_16x16x32_f16(af, bf[1], acc[ft][1], 0, 0, 0);
            }
        }
        #pragma unroll
        for (int ft = 0; ft < 4; ++ft)
            #pragma unroll
            for (int bt = 0; bt < 2; ++bt) {
                half4 hv;
                #pragma unroll
                for (int r = 0; r < 4; ++r) hv[r] = (_Float16)fast_tanh(acc[ft][bt][r]);
                *(half4*)&hs[w][bt * 16 + c][ft * 16 + g * 4] = hv;
            }
    }

    // ================= head: [64 -> 8] fp32 math, f16 weights, wave-local =================
    const int rl = l >> 1;           // row within wave (0..31)
    const int half = l & 1;          // output half (o = half*4 .. +3)
    const size_t grow = (size_t)rowbase + rl;
    const int tk = task[grow];
    f32x4 hacc = *(const f32x4*)(hB + tk * OUTF + half * 4);
    const _Float16* wrow = hw16 + (size_t)tk * (HID * OUTF) + half * 4;
    #pragma unroll
    for (int ch = 0; ch < 8; ++ch) {
        half8 hv = *(const half8*)&hs[w][rl][ch * 8];
        #pragma unroll
        for (int i2 = 0; i2 < 8; ++i2) {
            float hvf = (float)hv[i2];
            half4 wv = *(const half4*)(wrow + (ch * 8 + i2) * OUTF);
            hacc[0] = fmaf(hvf, (float)wv[0], hacc[0]);
            hacc[1] = fmaf(hvf, (float)wv[1], hacc[1]);
            hacc[2] = fmaf(hvf, (float)wv[2], hacc[2]);
            hacc[3] = fmaf(hvf, (float)wv[3], hacc[3]);
        }
    }
    *(f32x4*)(out + grow * OUTF + half * 4) = hacc;
}

extern "C" void kernel_launch(void* const* d_in, const int* in_sizes, int n_in,
                              void* d_out, int out_size, void* d_ws, size_t ws_size,
                              hipStream_t stream) {
    const float* x    = (const float*)d_in[0];
    const int*   task = (const int*)  d_in[1];
    const float* W0   = (const float*)d_in[2];
    const float* b0   = (const float*)d_in[3];
    const float* W1   = (const float*)d_in[4];
    const float* b1   = (const float*)d_in[5];
    const float* W2   = (const float*)d_in[6];
    const float* b2   = (const float*)d_in[7];
    const float* hW   = (const float*)d_in[8];
    const float* hB   = (const float*)d_in[9];
    float* out = (float*)d_out;
    _Float16* ws = (_Float16*)d_ws;

    prep_kernel<<<64, 256, 0, stream>>>(W0, W1, W2, hW, ws);
    mtn_mfma_kernel<<<BN / ROWS, NTHR, 0, stream>>>(x, task, b0, b1, b2, hB, ws, out);
}